// Round 1
// baseline (172.258 us; speedup 1.0000x reference)
//
#include <hip/hip_runtime.h>
#include <math.h>

// ---- config constants (float32, matching the reference exactly) ----
namespace {
constexpr float D_E   = 0.8187307530779818f;   // exp(-1/5)
constexpr float D_I   = 0.9048374180359595f;   // exp(-1/10)
constexpr float D_N   = 0.9900498337491681f;   // exp(-1/100)
constexpr float D_GB  = 0.9975031223974601f;   // exp(-1/400)
constexpr float D_CA  = 0.9512294245007140f;   // exp(-1/20)
// gAd is identically zero: gAd0 = 0 and ADAPT_INC = 0 -> gAd = gAd*D_AD + spike*0 = 0
// so the adaptation current gAd*(E_ADAPT - v_s) is exactly 0.0f every step; dropped.

constexpr float DT      = 1.0f;
constexpr float G_L     = 0.05f;
constexpr float E_L     = 0.0f;
constexpr float G_L_D   = 0.03f;
constexpr float DT_C_D  = 2.0f;                // DT / C_D (C_D = 0.5)
constexpr float G_C     = 0.05f;
constexpr float E_E     = 3.0f;
constexpr float E_I     = -0.5f;
constexpr float E_NMDA  = 3.0f;
constexpr float E_GABA_B= -0.8f;
constexpr float E_CA    = 4.0f;
constexpr float V_TH    = 1.0f;
constexpr float V_RESET = 0.0f;
constexpr float TAU_REF = 5.0f;
constexpr float MG_K    = 5.0f;
constexpr float MG_VHALF= 0.5f;
constexpr float THETA_CA= 2.0f;
constexpr float G_CA_SPIKE = 0.3f;
constexpr float BAP_AMP = 0.3f;
} // namespace

__device__ __forceinline__ void lif_step(
    float in_Eb, float in_Ib, float in_Nb, float in_GB,
    float in_Ea, float in_Ia, float in_Na,
    float& v_s, float& v_d,
    float& gEb, float& gIb, float& gNb, float& gGB,
    float& gEa, float& gIa, float& gNa, float& gCa, float& ref,
    float& spike_out, float& v_out)
{
    gEb = gEb * D_E  + in_Eb;
    gIb = gIb * D_I  + in_Ib;
    gNb = gNb * D_N  + in_Nb;
    gGB = gGB * D_GB + in_GB;
    gEa = gEa * D_E  + in_Ea;
    gIa = gIa * D_I  + in_Ia;
    gNa = gNa * D_N  + in_Na;
    gCa = gCa * D_CA;

    const float mg_s = 1.0f / (1.0f + expf(-MG_K * (v_s - MG_VHALF)));
    const float mg_d = 1.0f / (1.0f + expf(-MG_K * (v_d - MG_VHALF)));

    const float I_s = G_L * (E_L - v_s) + gEb * (E_E - v_s) + gIb * (E_I - v_s)
                    + gNb * mg_s * (E_NMDA - v_s) + gGB * (E_GABA_B - v_s)
                    + G_C * (v_d - v_s);
    const float I_d = G_L_D * (E_L - v_d) + gEa * (E_E - v_d) + gIa * (E_I - v_d)
                    + gNa * mg_d * (E_NMDA - v_d) + gCa * (E_CA - v_d)
                    + G_C * (v_s - v_d);

    const bool refractory = ref > 0.0f;
    v_s = refractory ? V_RESET : (v_s + DT * I_s);
    v_d = v_d + DT_C_D * I_d;

    const bool spike = (v_s >= V_TH) && !refractory;
    const float spike_f = spike ? 1.0f : 0.0f;
    v_s = spike ? V_RESET : v_s;
    ref = spike ? TAU_REF : fmaxf(ref - DT, 0.0f);
    // (gAd update dropped — identically zero)
    v_d = spike ? (v_d + BAP_AMP * (E_CA - v_d)) : v_d;
    gCa = gCa + ((v_d >= THETA_CA) ? G_CA_SPIKE : 0.0f);

    spike_out = spike_f;
    v_out = v_s;
}

// Vectorized: one thread simulates 4 consecutive neurons (16 B/lane loads).
__global__ __launch_bounds__(256)
void lif_vec4_kernel(const float* __restrict__ pEb, const float* __restrict__ pIb,
                     const float* __restrict__ pNb, const float* __restrict__ pGB,
                     const float* __restrict__ pEa, const float* __restrict__ pIa,
                     const float* __restrict__ pNa,
                     float* __restrict__ out, int N, int T)
{
    const long long tid  = (long long)blockIdx.x * blockDim.x + threadIdx.x;
    const long long base = tid * 4;
    if (base >= N) return;

    float v_s[4] = {E_L, E_L, E_L, E_L};
    float v_d[4] = {E_L, E_L, E_L, E_L};
    float gEb[4] = {}, gIb[4] = {}, gNb[4] = {}, gGB[4] = {};
    float gEa[4] = {}, gIa[4] = {}, gNa[4] = {}, gCa[4] = {}, ref[4] = {};

    const size_t vtrace_off = (size_t)T * (size_t)N;

    for (int t = 0; t < T; ++t) {
        const size_t off = (size_t)t * (size_t)N + (size_t)base;
        const float4 iEb = *(const float4*)(pEb + off);
        const float4 iIb = *(const float4*)(pIb + off);
        const float4 iNb = *(const float4*)(pNb + off);
        const float4 iGB = *(const float4*)(pGB + off);
        const float4 iEa = *(const float4*)(pEa + off);
        const float4 iIa = *(const float4*)(pIa + off);
        const float4 iNa = *(const float4*)(pNa + off);
        const float* fEb = reinterpret_cast<const float*>(&iEb);
        const float* fIb = reinterpret_cast<const float*>(&iIb);
        const float* fNb = reinterpret_cast<const float*>(&iNb);
        const float* fGB = reinterpret_cast<const float*>(&iGB);
        const float* fEa = reinterpret_cast<const float*>(&iEa);
        const float* fIa = reinterpret_cast<const float*>(&iIa);
        const float* fNa = reinterpret_cast<const float*>(&iNa);

        float4 osp, ov;
        float* sp = reinterpret_cast<float*>(&osp);
        float* vv = reinterpret_cast<float*>(&ov);

        #pragma unroll
        for (int j = 0; j < 4; ++j) {
            lif_step(fEb[j], fIb[j], fNb[j], fGB[j], fEa[j], fIa[j], fNa[j],
                     v_s[j], v_d[j],
                     gEb[j], gIb[j], gNb[j], gGB[j],
                     gEa[j], gIa[j], gNa[j], gCa[j], ref[j],
                     sp[j], vv[j]);
        }

        *reinterpret_cast<float4*>(out + off)              = osp;
        *reinterpret_cast<float4*>(out + vtrace_off + off) = ov;
    }
}

// Scalar fallback for N not divisible by 4 (not expected with N = 500000).
__global__ __launch_bounds__(256)
void lif_scalar_kernel(const float* __restrict__ pEb, const float* __restrict__ pIb,
                       const float* __restrict__ pNb, const float* __restrict__ pGB,
                       const float* __restrict__ pEa, const float* __restrict__ pIa,
                       const float* __restrict__ pNa,
                       float* __restrict__ out, int N, int T)
{
    const long long i = (long long)blockIdx.x * blockDim.x + threadIdx.x;
    if (i >= N) return;

    float v_s = E_L, v_d = E_L;
    float gEb = 0, gIb = 0, gNb = 0, gGB = 0;
    float gEa = 0, gIa = 0, gNa = 0, gCa = 0, ref = 0;

    const size_t vtrace_off = (size_t)T * (size_t)N;

    for (int t = 0; t < T; ++t) {
        const size_t off = (size_t)t * (size_t)N + (size_t)i;
        float sp, vv;
        lif_step(pEb[off], pIb[off], pNb[off], pGB[off], pEa[off], pIa[off], pNa[off],
                 v_s, v_d, gEb, gIb, gNb, gGB, gEa, gIa, gNa, gCa, ref, sp, vv);
        out[off]              = sp;
        out[vtrace_off + off] = vv;
    }
}

extern "C" void kernel_launch(void* const* d_in, const int* in_sizes, int n_in,
                              void* d_out, int out_size, void* d_ws, size_t ws_size,
                              hipStream_t stream) {
    const float* pEb = (const float*)d_in[0];  // g_exc_basal
    const float* pIb = (const float*)d_in[1];  // g_inh_basal
    const float* pNb = (const float*)d_in[2];  // g_nmda_basal
    const float* pGB = (const float*)d_in[3];  // g_gaba_b_in
    const float* pEa = (const float*)d_in[4];  // g_exc_apical
    const float* pIa = (const float*)d_in[5];  // g_inh_apical
    const float* pNa = (const float*)d_in[6];  // g_nmda_apical
    float* out = (float*)d_out;

    const int T = 50;
    const int N = in_sizes[0] / T;

    if ((N & 3) == 0) {
        const int threads = N / 4;
        const int blocks = (threads + 255) / 256;
        lif_vec4_kernel<<<blocks, 256, 0, stream>>>(pEb, pIb, pNb, pGB, pEa, pIa, pNa,
                                                    out, N, T);
    } else {
        const int blocks = (N + 255) / 256;
        lif_scalar_kernel<<<blocks, 256, 0, stream>>>(pEb, pIb, pNb, pGB, pEa, pIa, pNa,
                                                      out, N, T);
    }
}